// Round 1
// baseline (7328.441 us; speedup 1.0000x reference)
//
#include <hip/hip_runtime.h>
#include <hip/hip_bf16.h>

#define B_ 2
#define S_ 2048
#define H_ 2048
#define NH_ 16
#define NKV_ 4
#define HD_ 128
#define M_ (B_*S_)

typedef signed char s8;

__device__ __forceinline__ float loadf(const void* p, long i, int isb){
  if (isb) return __bfloat162float(((const __hip_bfloat16*)p)[i]);
  return ((const float*)p)[i];
}

__device__ __forceinline__ int dot4(int a, int b, int c){
  c += (int)(s8)(a      ) * (int)(s8)(b      );
  c += (int)(s8)(a >> 8 ) * (int)(s8)(b >> 8 );
  c += (int)(s8)(a >> 16) * (int)(s8)(b >> 16);
  c += (int)(s8)(a >> 24) * (int)(s8)(b >> 24);
  return c;
}

// ---- dtype sniffer: low 16 bits of each word look like a bf16 of N(0,1)? ----
__global__ void k_detect(const unsigned int* x, int* flag){
  __shared__ int sh[256];
  int t = threadIdx.x, c = 0;
  for (int i = t; i < 2048; i += 256){
    unsigned e = (x[i] >> 7) & 0xFF;          // exponent byte of low half
    if (e >= 90 && e <= 150) c++;
  }
  sh[t] = c; __syncthreads();
  for (int k = 128; k > 0; k >>= 1){ if (t < k) sh[t] += sh[t+k]; __syncthreads(); }
  if (t == 0) flag[0] = (sh[0] > 1228) ? 1 : 0;   // bf16 ~2048, fp32 ~488
}

// ---- sum |w| ----
__global__ void k_wsum(const void* w, long n, const int* flag, float* acc){
  __shared__ float sh[256];
  int isb = *flag;
  long stride = (long)gridDim.x * 256;
  float s = 0.f;
  for (long i = (long)blockIdx.x*256 + threadIdx.x; i < n; i += stride)
    s += fabsf(loadf(w, i, isb));
  sh[threadIdx.x] = s; __syncthreads();
  for (int k = 128; k > 0; k >>= 1){ if (threadIdx.x < k) sh[threadIdx.x] += sh[threadIdx.x+k]; __syncthreads(); }
  if (threadIdx.x == 0) atomicAdd(acc, sh[0]);
}

__global__ void k_wfin(const float* wsum, float* wscale){
  const float cnt[4] = { (float)((long)H_*H_), (float)((long)NKV_*HD_*H_),
                         (float)((long)NKV_*HD_*H_), (float)((long)H_*H_) };
  int t = threadIdx.x;
  if (t < 4){
    float m = wsum[t] / cnt[t];
    m = fmaxf(m, 1e-5f);
    wscale[t] = 1.0f / m;       // ws multiplier (ref: ws = 1/clip(mean,1e-5))
  }
}

__global__ void k_wquant(const void* w, long n, const int* flag, const float* wscale, int wi, s8* out){
  int isb = *flag; float sc = wscale[wi];
  long stride = (long)gridDim.x * 256;
  for (long i = (long)blockIdx.x*256 + threadIdx.x; i < n; i += stride){
    float v = rintf(loadf(w, i, isb) * sc);
    v = fminf(fmaxf(v, -1.f), 1.f);
    out[i] = (s8)v;
  }
}

// ---- per-token activation quant (typed input) ----
__global__ void k_aquant_in(const void* x, const int* flag, float* srow, s8* xq){
  __shared__ float sh[256];
  int isb = *flag; int r = blockIdx.x, t = threadIdx.x;
  long base = (long)r * H_;
  float mx = 0.f;
  for (int i = t; i < H_; i += 256) mx = fmaxf(mx, fabsf(loadf(x, base+i, isb)));
  sh[t] = mx; __syncthreads();
  for (int k = 128; k > 0; k >>= 1){ if (t < k) sh[t] = fmaxf(sh[t], sh[t+k]); __syncthreads(); }
  float s = 127.0f / fmaxf(sh[0], 1e-5f);
  if (t == 0) srow[r] = s;
  for (int i = t; i < H_; i += 256){
    float v = rintf(loadf(x, base+i, isb) * s);
    v = fminf(fmaxf(v, -128.f), 127.f);
    xq[base+i] = (s8)v;
  }
}

// ---- per-token activation quant (fp32 input) ----
__global__ void k_aquant_f32(const float* x, float* srow, s8* xq){
  __shared__ float sh[256];
  int r = blockIdx.x, t = threadIdx.x;
  long base = (long)r * H_;
  float mx = 0.f;
  for (int i = t; i < H_; i += 256) mx = fmaxf(mx, fabsf(x[base+i]));
  sh[t] = mx; __syncthreads();
  for (int k = 128; k > 0; k >>= 1){ if (t < k) sh[t] = fmaxf(sh[t], sh[t+k]); __syncthreads(); }
  float s = 127.0f / fmaxf(sh[0], 1e-5f);
  if (t == 0) srow[r] = s;
  for (int i = t; i < H_; i += 256){
    float v = rintf(x[base+i] * s);
    v = fminf(fmaxf(v, -128.f), 127.f);
    xq[base+i] = (s8)v;
  }
}

// ---- int8 GEMM: C[m][n] = sum_k A[m][k]*Bw[n][k], dequant epilogue ----
#define GBM 16
#define GBN 64
#define GBK 128
#define LDP 144

__global__ __launch_bounds__(256) void k_gemm(const s8* __restrict__ A, const s8* __restrict__ Bw,
      const float* __restrict__ srow, const float* __restrict__ wscale, int wi,
      float* __restrict__ C, int N){
  __shared__ s8 As[GBM*LDP];
  __shared__ s8 Bs[GBN*LDP];
  int tid = threadIdx.x, ty = tid >> 4, tx = tid & 15;
  long arow = (long)blockIdx.y * GBM, bcol = (long)blockIdx.x * GBN;
  int acc0=0, acc1=0, acc2=0, acc3=0;
  const int K = H_;
  for (int k0 = 0; k0 < K; k0 += GBK){
    { int t8 = tid*8, r = t8 >> 7, c = t8 & 127;
      *(unsigned long long*)&As[r*LDP + c] =
        *(const unsigned long long*)(A + (arow+r)*K + k0 + c); }
    #pragma unroll
    for (int rep = 0; rep < 2; rep++){
      int t16 = (tid + rep*256)*16, r = t16 >> 7, c = t16 & 127;
      *(int4*)&Bs[r*LDP + c] = *(const int4*)(Bw + (bcol+r)*K + k0 + c);
    }
    __syncthreads();
    #pragma unroll
    for (int kk = 0; kk < GBK; kk += 16){
      int4 a  = *(const int4*)&As[ty*LDP + kk];
      int4 b0 = *(const int4*)&Bs[(tx    )*LDP + kk];
      int4 b1 = *(const int4*)&Bs[(tx+16)*LDP + kk];
      int4 b2 = *(const int4*)&Bs[(tx+32)*LDP + kk];
      int4 b3 = *(const int4*)&Bs[(tx+48)*LDP + kk];
      acc0=dot4(a.x,b0.x,acc0); acc0=dot4(a.y,b0.y,acc0); acc0=dot4(a.z,b0.z,acc0); acc0=dot4(a.w,b0.w,acc0);
      acc1=dot4(a.x,b1.x,acc1); acc1=dot4(a.y,b1.y,acc1); acc1=dot4(a.z,b1.z,acc1); acc1=dot4(a.w,b1.w,acc1);
      acc2=dot4(a.x,b2.x,acc2); acc2=dot4(a.y,b2.y,acc2); acc2=dot4(a.z,b2.z,acc2); acc2=dot4(a.w,b2.w,acc2);
      acc3=dot4(a.x,b3.x,acc3); acc3=dot4(a.y,b3.y,acc3); acc3=dot4(a.z,b3.z,acc3); acc3=dot4(a.w,b3.w,acc3);
    }
    __syncthreads();
  }
  float sc = 1.0f / (srow[arow+ty] * wscale[wi]);
  long cb = (arow+ty)*(long)N + bcol + tx;
  C[cb]    = acc0*sc; C[cb+16] = acc1*sc; C[cb+32] = acc2*sc; C[cb+48] = acc3*sc;
}

// ---- same GEMM, writes final output in detected dtype ----
__global__ __launch_bounds__(256) void k_gemm_out(const s8* __restrict__ A, const s8* __restrict__ Bw,
      const float* __restrict__ srow, const float* __restrict__ wscale, int wi,
      const int* __restrict__ flag, void* __restrict__ out, int N){
  __shared__ s8 As[GBM*LDP];
  __shared__ s8 Bs[GBN*LDP];
  int tid = threadIdx.x, ty = tid >> 4, tx = tid & 15;
  long arow = (long)blockIdx.y * GBM, bcol = (long)blockIdx.x * GBN;
  int acc0=0, acc1=0, acc2=0, acc3=0;
  const int K = H_;
  for (int k0 = 0; k0 < K; k0 += GBK){
    { int t8 = tid*8, r = t8 >> 7, c = t8 & 127;
      *(unsigned long long*)&As[r*LDP + c] =
        *(const unsigned long long*)(A + (arow+r)*K + k0 + c); }
    #pragma unroll
    for (int rep = 0; rep < 2; rep++){
      int t16 = (tid + rep*256)*16, r = t16 >> 7, c = t16 & 127;
      *(int4*)&Bs[r*LDP + c] = *(const int4*)(Bw + (bcol+r)*K + k0 + c);
    }
    __syncthreads();
    #pragma unroll
    for (int kk = 0; kk < GBK; kk += 16){
      int4 a  = *(const int4*)&As[ty*LDP + kk];
      int4 b0 = *(const int4*)&Bs[(tx    )*LDP + kk];
      int4 b1 = *(const int4*)&Bs[(tx+16)*LDP + kk];
      int4 b2 = *(const int4*)&Bs[(tx+32)*LDP + kk];
      int4 b3 = *(const int4*)&Bs[(tx+48)*LDP + kk];
      acc0=dot4(a.x,b0.x,acc0); acc0=dot4(a.y,b0.y,acc0); acc0=dot4(a.z,b0.z,acc0); acc0=dot4(a.w,b0.w,acc0);
      acc1=dot4(a.x,b1.x,acc1); acc1=dot4(a.y,b1.y,acc1); acc1=dot4(a.z,b1.z,acc1); acc1=dot4(a.w,b1.w,acc1);
      acc2=dot4(a.x,b2.x,acc2); acc2=dot4(a.y,b2.y,acc2); acc2=dot4(a.z,b2.z,acc2); acc2=dot4(a.w,b2.w,acc2);
      acc3=dot4(a.x,b3.x,acc3); acc3=dot4(a.y,b3.y,acc3); acc3=dot4(a.z,b3.z,acc3); acc3=dot4(a.w,b3.w,acc3);
    }
    __syncthreads();
  }
  float sc = 1.0f / (srow[arow+ty] * wscale[wi]);
  long cb = (arow+ty)*(long)N + bcol + tx;
  float v0 = acc0*sc, v1 = acc1*sc, v2 = acc2*sc, v3 = acc3*sc;
  if (*flag){
    __hip_bfloat16* o = (__hip_bfloat16*)out;
    o[cb]    = __float2bfloat16(v0); o[cb+16] = __float2bfloat16(v1);
    o[cb+32] = __float2bfloat16(v2); o[cb+48] = __float2bfloat16(v3);
  } else {
    float* o = (float*)out;
    o[cb] = v0; o[cb+16] = v1; o[cb+32] = v2; o[cb+48] = v3;
  }
}

// ---- RoPE in place on q and k ----
__global__ void k_rope(float* q, float* k){
  int row = blockIdx.x, hh = blockIdx.y, d = threadIdx.x;   // d in [0,64)
  int pos = row & (S_-1);
  float inv = powf(10000.0f, -(float)d * (1.0f/64.0f));
  float a = (float)pos * inv;
  float sn, cs; sincosf(a, &sn, &cs);
  float* p;
  if (hh < NH_) p = q + ((long)row*NH_ + hh)*HD_;
  else          p = k + ((long)row*NKV_ + (hh-NH_))*HD_;
  float x0 = p[d], x1 = p[d+64];
  p[d]    = x0*cs - x1*sn;
  p[d+64] = x1*cs + x0*sn;
}

// ---- causal GQA attention, online softmax; one block per (b,h,row) ----
__global__ __launch_bounds__(256) void k_attn(const float* __restrict__ qb, const float* __restrict__ kb,
                                              const float* __restrict__ vb, float* __restrict__ ob){
  int m = blockIdx.x, h = blockIdx.y, b = blockIdx.z;
  int t = threadIdx.x;
  int kvh = h >> 2;
  const float* qr = qb + (((long)b*S_ + m)*NH_ + h)*HD_;
  const float* kbase = kb + ((long)b*S_*NKV_ + kvh)*HD_;
  const float* vbase = vb + ((long)b*S_*NKV_ + kvh)*HD_;
  __shared__ float qs[HD_];
  __shared__ float sc[256];
  __shared__ float red[256];
  __shared__ float sh_m, sh_l;
  if (t < HD_) qs[t] = qr[t] * 0.08838834764831845f;
  if (t == 0){ sh_m = -1e30f; sh_l = 0.f; }
  float acc = 0.f;
  int nk = m + 1;
  __syncthreads();
  for (int j0 = 0; j0 < nk; j0 += 256){
    int jj = j0 + t;
    float sj = -1e30f;
    if (jj < nk){
      const float4* kr = (const float4*)(kbase + (long)jj*(NKV_*HD_));
      float s0 = 0.f;
      #pragma unroll
      for (int d4 = 0; d4 < HD_/4; d4++){
        float4 kv = kr[d4];
        s0 += qs[d4*4+0]*kv.x + qs[d4*4+1]*kv.y + qs[d4*4+2]*kv.z + qs[d4*4+3]*kv.w;
      }
      sj = s0;
    }
    red[t] = sj; __syncthreads();
    for (int k = 128; k > 0; k >>= 1){ if (t < k) red[t] = fmaxf(red[t], red[t+k]); __syncthreads(); }
    float nm = fmaxf(sh_m, red[0]);
    float alpha = expf(sh_m - nm);
    float p = (jj < nk) ? expf(sj - nm) : 0.f;
    __syncthreads();                       // done reading red[0]/sh_m
    sc[t] = p; red[t] = p; __syncthreads();
    for (int k = 128; k > 0; k >>= 1){ if (t < k) red[t] += red[t+k]; __syncthreads(); }
    float psum = red[0];
    if (t < HD_){
      float a2 = 0.f;
      int jn = min(256, nk - j0);
      for (int u = 0; u < jn; u++)
        a2 += sc[u] * vbase[(long)(j0+u)*(NKV_*HD_) + t];
      acc = acc*alpha + a2;
    }
    if (t == 0){ sh_l = sh_l*alpha + psum; sh_m = nm; }
    __syncthreads();
  }
  if (t < HD_){
    float* orow = ob + ((long)b*S_ + m)*H_ + h*HD_;
    orow[t] = acc / sh_l;
  }
}

extern "C" void kernel_launch(void* const* d_in, const int* in_sizes, int n_in,
                              void* d_out, int out_size, void* d_ws, size_t ws_size,
                              hipStream_t stream){
  (void)in_sizes; (void)n_in; (void)out_size; (void)ws_size;
  const void* x  = d_in[0];
  const void* Wq = d_in[2];
  const void* Wk = d_in[3];
  const void* Wv = d_in[4];
  const void* Wo = d_in[5];
  char* ws = (char*)d_ws;
  size_t o = 0;
  auto alloc = [&](size_t b){ size_t r = o; o += (b + 255) & ~(size_t)255; return r; };
  size_t META = alloc(256);
  float* wsum   = (float*)(ws + META);
  float* wscale = (float*)(ws + META + 16);
  int*   flag   = (int*)  (ws + META + 32);
  float* s_x = (float*)(ws + alloc((size_t)M_*4));
  float* s_a = (float*)(ws + alloc((size_t)M_*4));
  s8* xq  = (s8*)(ws + alloc((size_t)M_*H_));
  s8* wqq = (s8*)(ws + alloc((size_t)H_*H_));
  s8* wkq = (s8*)(ws + alloc((size_t)NKV_*HD_*H_));
  s8* wvq = (s8*)(ws + alloc((size_t)NKV_*HD_*H_));
  s8* woq = (s8*)(ws + alloc((size_t)H_*H_));
  float* qb = (float*)(ws + alloc((size_t)M_*NH_*HD_*4));
  float* kb = (float*)(ws + alloc((size_t)M_*NKV_*HD_*4));
  float* vb = (float*)(ws + alloc((size_t)M_*NKV_*HD_*4));
  float* ab = (float*)(ws + alloc((size_t)M_*H_*4));
  s8* aq = xq;   // reuse: xq dead after the QKV GEMMs

  hipMemsetAsync(ws + META, 0, 64, stream);
  k_detect<<<1,256,0,stream>>>((const unsigned int*)x, flag);

  long nqq = (long)H_*H_, nkk = (long)NKV_*HD_*H_;
  k_wsum<<<512,256,0,stream>>>(Wq, nqq, flag, &wsum[0]);
  k_wsum<<<256,256,0,stream>>>(Wk, nkk, flag, &wsum[1]);
  k_wsum<<<256,256,0,stream>>>(Wv, nkk, flag, &wsum[2]);
  k_wsum<<<512,256,0,stream>>>(Wo, nqq, flag, &wsum[3]);
  k_wfin<<<1,64,0,stream>>>(wsum, wscale);
  k_wquant<<<1024,256,0,stream>>>(Wq, nqq, flag, wscale, 0, wqq);
  k_wquant<<<256,256,0,stream>>>(Wk, nkk, flag, wscale, 1, wkq);
  k_wquant<<<256,256,0,stream>>>(Wv, nkk, flag, wscale, 2, wvq);
  k_wquant<<<1024,256,0,stream>>>(Wo, nqq, flag, wscale, 3, woq);

  k_aquant_in<<<M_,256,0,stream>>>(x, flag, s_x, xq);

  dim3 gq(H_/GBN, M_/GBM), gkv((NKV_*HD_)/GBN, M_/GBM);
  k_gemm<<<gq, 256, 0, stream>>>(xq, wqq, s_x, wscale, 0, qb, H_);
  k_gemm<<<gkv,256, 0, stream>>>(xq, wkq, s_x, wscale, 1, kb, NKV_*HD_);
  k_gemm<<<gkv,256, 0, stream>>>(xq, wvq, s_x, wscale, 2, vb, NKV_*HD_);

  dim3 gr(M_, NH_+NKV_);
  k_rope<<<gr, 64, 0, stream>>>(qb, kb);

  dim3 ga(S_, NH_, B_);
  k_attn<<<ga, 256, 0, stream>>>(qb, kb, vb, ab);

  k_aquant_f32<<<M_,256,0,stream>>>(ab, s_a, aq);
  k_gemm_out<<<gq,256,0,stream>>>(aq, woq, s_a, wscale, 3, flag, d_out, H_);
}

// Round 2
// 2691.319 us; speedup vs baseline: 2.7230x; 2.7230x over previous
//
#include <hip/hip_runtime.h>
#include <hip/hip_bf16.h>

#define B_ 2
#define S_ 2048
#define H_ 2048
#define NH_ 16
#define NKV_ 4
#define HD_ 128
#define M_ (B_*S_)
#define KVD_ (NKV_*HD_)

typedef signed char s8;
typedef __attribute__((ext_vector_type(8))) short short8;
typedef __attribute__((ext_vector_type(4))) short short4v;
typedef __attribute__((ext_vector_type(4))) float f32x4;

__device__ __forceinline__ float loadf(const void* p, long i, int isb){
  if (isb) return __bfloat162float(((const __hip_bfloat16*)p)[i]);
  return ((const float*)p)[i];
}

__device__ __forceinline__ unsigned short f2bf(float f){
  union { float f; unsigned u; } v; v.f = f;
  unsigned r = v.u + 0x7FFF + ((v.u >> 16) & 1);
  return (unsigned short)(r >> 16);
}

__device__ __forceinline__ int dot4(int a, int b, int c){
  c += (int)(s8)(a      ) * (int)(s8)(b      );
  c += (int)(s8)(a >> 8 ) * (int)(s8)(b >> 8 );
  c += (int)(s8)(a >> 16) * (int)(s8)(b >> 16);
  c += (int)(s8)(a >> 24) * (int)(s8)(b >> 24);
  return c;
}

// ---- dtype sniffer ----
__global__ void k_detect(const unsigned int* x, int* flag){
  __shared__ int sh[256];
  int t = threadIdx.x, c = 0;
  for (int i = t; i < 2048; i += 256){
    unsigned e = (x[i] >> 7) & 0xFF;
    if (e >= 90 && e <= 150) c++;
  }
  sh[t] = c; __syncthreads();
  for (int k = 128; k > 0; k >>= 1){ if (t < k) sh[t] += sh[t+k]; __syncthreads(); }
  if (t == 0) flag[0] = (sh[0] > 1228) ? 1 : 0;
}

// ---- sum |w| ----
__global__ void k_wsum(const void* w, long n, const int* flag, float* acc){
  __shared__ float sh[256];
  int isb = *flag;
  long stride = (long)gridDim.x * 256;
  float s = 0.f;
  for (long i = (long)blockIdx.x*256 + threadIdx.x; i < n; i += stride)
    s += fabsf(loadf(w, i, isb));
  sh[threadIdx.x] = s; __syncthreads();
  for (int k = 128; k > 0; k >>= 1){ if (threadIdx.x < k) sh[threadIdx.x] += sh[threadIdx.x+k]; __syncthreads(); }
  if (threadIdx.x == 0) atomicAdd(acc, sh[0]);
}

__global__ void k_wfin(const float* wsum, float* wscale){
  const float cnt[4] = { (float)((long)H_*H_), (float)((long)KVD_*H_),
                         (float)((long)KVD_*H_), (float)((long)H_*H_) };
  int t = threadIdx.x;
  if (t < 4){
    float m = wsum[t] / cnt[t];
    m = fmaxf(m, 1e-5f);
    wscale[t] = 1.0f / m;
  }
}

__global__ void k_wquant(const void* w, long n, const int* flag, const float* wscale, int wi, s8* out){
  int isb = *flag; float sc = wscale[wi];
  long stride = (long)gridDim.x * 256;
  for (long i = (long)blockIdx.x*256 + threadIdx.x; i < n; i += stride){
    float v = rintf(loadf(w, i, isb) * sc);
    v = fminf(fmaxf(v, -1.f), 1.f);
    out[i] = (s8)v;
  }
}

// ---- per-token activation quant (typed input) ----
__global__ void k_aquant_in(const void* x, const int* flag, float* srow, s8* xq){
  __shared__ float sh[256];
  int isb = *flag; int r = blockIdx.x, t = threadIdx.x;
  long base = (long)r * H_;
  float mx = 0.f;
  for (int i = t; i < H_; i += 256) mx = fmaxf(mx, fabsf(loadf(x, base+i, isb)));
  sh[t] = mx; __syncthreads();
  for (int k = 128; k > 0; k >>= 1){ if (t < k) sh[t] = fmaxf(sh[t], sh[t+k]); __syncthreads(); }
  float s = 127.0f / fmaxf(sh[0], 1e-5f);
  if (t == 0) srow[r] = s;
  for (int i = t; i < H_; i += 256){
    float v = rintf(loadf(x, base+i, isb) * s);
    v = fminf(fmaxf(v, -128.f), 127.f);
    xq[base+i] = (s8)v;
  }
}

// ---- per-token activation quant (fp32 input) ----
__global__ void k_aquant_f32(const float* x, float* srow, s8* xq){
  __shared__ float sh[256];
  int r = blockIdx.x, t = threadIdx.x;
  long base = (long)r * H_;
  float mx = 0.f;
  for (int i = t; i < H_; i += 256) mx = fmaxf(mx, fabsf(x[base+i]));
  sh[t] = mx; __syncthreads();
  for (int k = 128; k > 0; k >>= 1){ if (t < k) sh[t] = fmaxf(sh[t], sh[t+k]); __syncthreads(); }
  float s = 127.0f / fmaxf(sh[0], 1e-5f);
  if (t == 0) srow[r] = s;
  for (int i = t; i < H_; i += 256){
    float v = rintf(x[base+i] * s);
    v = fminf(fmaxf(v, -128.f), 127.f);
    xq[base+i] = (s8)v;
  }
}

// ---- int8 GEMM ----
#define GBM 16
#define GBN 64
#define GBK 128
#define LDP 144

#define GEMM_BODY \
  __shared__ s8 As[GBM*LDP]; \
  __shared__ s8 Bs[GBN*LDP]; \
  int tid = threadIdx.x, ty = tid >> 4, tx = tid & 15; \
  long arow = (long)blockIdx.y * GBM, bcol = (long)blockIdx.x * GBN; \
  int acc0=0, acc1=0, acc2=0, acc3=0; \
  const int K = H_; \
  for (int k0 = 0; k0 < K; k0 += GBK){ \
    { int t8 = tid*8, r = t8 >> 7, cc = t8 & 127; \
      *(unsigned long long*)&As[r*LDP + cc] = \
        *(const unsigned long long*)(A + (arow+r)*K + k0 + cc); } \
    _Pragma("unroll") \
    for (int rep = 0; rep < 2; rep++){ \
      int t16 = (tid + rep*256)*16, r = t16 >> 7, cc = t16 & 127; \
      *(int4*)&Bs[r*LDP + cc] = *(const int4*)(Bw + (bcol+r)*K + k0 + cc); \
    } \
    __syncthreads(); \
    _Pragma("unroll") \
    for (int kk = 0; kk < GBK; kk += 16){ \
      int4 a  = *(const int4*)&As[ty*LDP + kk]; \
      int4 b0 = *(const int4*)&Bs[(tx    )*LDP + kk]; \
      int4 b1 = *(const int4*)&Bs[(tx+16)*LDP + kk]; \
      int4 b2 = *(const int4*)&Bs[(tx+32)*LDP + kk]; \
      int4 b3 = *(const int4*)&Bs[(tx+48)*LDP + kk]; \
      acc0=dot4(a.x,b0.x,acc0); acc0=dot4(a.y,b0.y,acc0); acc0=dot4(a.z,b0.z,acc0); acc0=dot4(a.w,b0.w,acc0); \
      acc1=dot4(a.x,b1.x,acc1); acc1=dot4(a.y,b1.y,acc1); acc1=dot4(a.z,b1.z,acc1); acc1=dot4(a.w,b1.w,acc1); \
      acc2=dot4(a.x,b2.x,acc2); acc2=dot4(a.y,b2.y,acc2); acc2=dot4(a.z,b2.z,acc2); acc2=dot4(a.w,b2.w,acc2); \
      acc3=dot4(a.x,b3.x,acc3); acc3=dot4(a.y,b3.y,acc3); acc3=dot4(a.z,b3.z,acc3); acc3=dot4(a.w,b3.w,acc3); \
    } \
    __syncthreads(); \
  }

__global__ __launch_bounds__(256) void k_gemm(const s8* __restrict__ A, const s8* __restrict__ Bw,
      const float* __restrict__ srow, const float* __restrict__ wscale, int wi,
      float* __restrict__ C, int N){
  GEMM_BODY
  float sc = 1.0f / (srow[arow+ty] * wscale[wi]);
  long cb = (arow+ty)*(long)N + bcol + tx;
  C[cb]    = acc0*sc; C[cb+16] = acc1*sc; C[cb+32] = acc2*sc; C[cb+48] = acc3*sc;
}

// V GEMM: writes bf16 transposed Vt[b][kv*hd][S]
__global__ __launch_bounds__(256) void k_gemm_vt(const s8* __restrict__ A, const s8* __restrict__ Bw,
      const float* __restrict__ srow, const float* __restrict__ wscale, int wi,
      unsigned short* __restrict__ Vt){
  GEMM_BODY
  float sc = 1.0f / (srow[arow+ty] * wscale[wi]);
  long mrow = arow + ty;
  long bb = mrow >> 11, sI = mrow & (S_-1);
  unsigned short* base = Vt + bb*(long)KVD_*S_ + sI;
  base[(long)(bcol+tx   )*S_] = f2bf(acc0*sc);
  base[(long)(bcol+tx+16)*S_] = f2bf(acc1*sc);
  base[(long)(bcol+tx+32)*S_] = f2bf(acc2*sc);
  base[(long)(bcol+tx+48)*S_] = f2bf(acc3*sc);
}

__global__ __launch_bounds__(256) void k_gemm_out(const s8* __restrict__ A, const s8* __restrict__ Bw,
      const float* __restrict__ srow, const float* __restrict__ wscale, int wi,
      const int* __restrict__ flag, void* __restrict__ out, int N){
  GEMM_BODY
  float sc = 1.0f / (srow[arow+ty] * wscale[wi]);
  long cb = (arow+ty)*(long)N + bcol + tx;
  float v0 = acc0*sc, v1 = acc1*sc, v2 = acc2*sc, v3 = acc3*sc;
  if (*flag){
    __hip_bfloat16* o = (__hip_bfloat16*)out;
    o[cb]    = __float2bfloat16(v0); o[cb+16] = __float2bfloat16(v1);
    o[cb+32] = __float2bfloat16(v2); o[cb+48] = __float2bfloat16(v3);
  } else {
    float* o = (float*)out;
    o[cb] = v0; o[cb+16] = v1; o[cb+32] = v2; o[cb+48] = v3;
  }
}

// ---- RoPE fp32 -> bf16; Q pre-scaled by 1/sqrt(HD) ----
__global__ void k_rope_cvt(const float* __restrict__ qf, const float* __restrict__ kf,
                           unsigned short* __restrict__ Qb, unsigned short* __restrict__ Kb){
  int row = blockIdx.x, hh = blockIdx.y, d = threadIdx.x;   // d in [0,64)
  int pos = row & (S_-1);
  float inv = powf(10000.0f, -(float)d * (1.0f/64.0f));
  float a = (float)pos * inv;
  float sn, cs; sincosf(a, &sn, &cs);
  if (hh < NH_){
    const float* p = qf + ((long)row*NH_ + hh)*HD_;
    unsigned short* q = Qb + ((long)row*NH_ + hh)*HD_;
    float x0 = p[d], x1 = p[d+64];
    const float sc = 0.08838834764831845f;
    q[d]    = f2bf((x0*cs - x1*sn)*sc);
    q[d+64] = f2bf((x1*cs + x0*sn)*sc);
  } else {
    int kh = hh - NH_;
    const float* p = kf + ((long)row*NKV_ + kh)*HD_;
    unsigned short* k = Kb + ((long)row*NKV_ + kh)*HD_;
    float x0 = p[d], x1 = p[d+64];
    k[d]    = f2bf(x0*cs - x1*sn);
    k[d+64] = f2bf(x1*cs + x0*sn);
  }
}

// ---- MFMA flash attention: 1 wave per (b,h,16-row q-tile) ----
__global__ __launch_bounds__(64) void k_attn_mfma(const unsigned short* __restrict__ Qb,
    const unsigned short* __restrict__ Kb, const unsigned short* __restrict__ Vt,
    float* __restrict__ ob){
  int qt = blockIdx.x, h = blockIdx.y, b = blockIdx.z;
  int lane = threadIdx.x, quad = lane >> 4, c = lane & 15;
  int kvh = h >> 2, q0 = qt * 16;
  short8 qf[4];
  #pragma unroll
  for (int f = 0; f < 4; f++)
    qf[f] = *(const short8*)(Qb + ((long)(b*S_ + q0 + c)*NH_ + h)*HD_ + f*32 + quad*8);
  const unsigned short* Kp = Kb + (long)b*S_*KVD_ + kvh*HD_;
  const unsigned short* Vp = Vt + ((long)b*KVD_ + kvh*HD_)*S_;
  f32x4 o[8];
  #pragma unroll
  for (int i = 0; i < 8; i++) o[i] = (f32x4){0.f,0.f,0.f,0.f};
  float m[4] = {-1e30f,-1e30f,-1e30f,-1e30f};
  float l[4] = {0.f,0.f,0.f,0.f};
  __shared__ unsigned short Pl[16*40];   // row stride 40 shorts: 8B-aligned frags, conflict-light
  int nk = q0 + 16;
  for (int kc = 0; kc < nk; kc += 32){
    f32x4 s[2];
    s[0] = (f32x4){0.f,0.f,0.f,0.f};
    s[1] = (f32x4){0.f,0.f,0.f,0.f};
    #pragma unroll
    for (int t = 0; t < 2; t++){
      int key = kc + t*16 + c;
      int ka = min(key, S_-1);
      #pragma unroll
      for (int f = 0; f < 4; f++){
        short8 kfr = *(const short8*)(Kp + (long)ka*KVD_ + f*32 + quad*8);
        s[t] = __builtin_amdgcn_mfma_f32_16x16x32_bf16(qf[f], kfr, s[t], 0, 0, 0);
      }
    }
    if (kc + 31 > q0){   // only the diagonal chunk needs masking
      #pragma unroll
      for (int t = 0; t < 2; t++){
        int key = kc + t*16 + c;
        #pragma unroll
        for (int r = 0; r < 4; r++)
          if (key > q0 + quad*4 + r) s[t][r] = -1e30f;
      }
    }
    float mr[4], alpha[4], rs[4];
    #pragma unroll
    for (int r = 0; r < 4; r++) mr[r] = fmaxf(s[0][r], s[1][r]);
    #pragma unroll
    for (int w = 1; w < 16; w <<= 1)
      #pragma unroll
      for (int r = 0; r < 4; r++) mr[r] = fmaxf(mr[r], __shfl_xor(mr[r], w, 64));
    #pragma unroll
    for (int r = 0; r < 4; r++){
      float mn = fmaxf(m[r], mr[r]);
      alpha[r] = __expf(m[r] - mn);
      m[r] = mn;
    }
    #pragma unroll
    for (int r = 0; r < 4; r++){
      float p0 = __expf(s[0][r] - m[r]);
      float p1 = __expf(s[1][r] - m[r]);
      s[0][r] = p0; s[1][r] = p1; rs[r] = p0 + p1;
    }
    #pragma unroll
    for (int w = 1; w < 16; w <<= 1)
      #pragma unroll
      for (int r = 0; r < 4; r++) rs[r] += __shfl_xor(rs[r], w, 64);
    #pragma unroll
    for (int r = 0; r < 4; r++) l[r] = l[r]*alpha[r] + rs[r];
    #pragma unroll
    for (int nt = 0; nt < 8; nt++)
      #pragma unroll
      for (int r = 0; r < 4; r++) o[nt][r] *= alpha[r];
    // P: C-layout -> LDS -> A-layout (bf16)
    #pragma unroll
    for (int t = 0; t < 2; t++)
      #pragma unroll
      for (int r = 0; r < 4; r++)
        Pl[(quad*4 + r)*40 + t*16 + c] = f2bf(s[t][r]);
    __syncthreads();
    short8 pf;
    {
      short4v a0 = *(const short4v*)&Pl[c*40 + quad*8];
      short4v a1 = *(const short4v*)&Pl[c*40 + quad*8 + 4];
      pf[0]=a0[0]; pf[1]=a0[1]; pf[2]=a0[2]; pf[3]=a0[3];
      pf[4]=a1[0]; pf[5]=a1[1]; pf[6]=a1[2]; pf[7]=a1[3];
    }
    __syncthreads();
    int kb0 = min(kc + quad*8, S_-8);   // OOB keys have p=0
    #pragma unroll
    for (int nt = 0; nt < 8; nt++){
      short8 vf = *(const short8*)(Vp + (long)(nt*16 + c)*S_ + kb0);
      o[nt] = __builtin_amdgcn_mfma_f32_16x16x32_bf16(pf, vf, o[nt], 0, 0, 0);
    }
  }
  float il[4];
  #pragma unroll
  for (int r = 0; r < 4; r++) il[r] = 1.0f / l[r];
  #pragma unroll
  for (int nt = 0; nt < 8; nt++)
    #pragma unroll
    for (int r = 0; r < 4; r++)
      ob[((long)(b*S_ + q0 + quad*4 + r))*H_ + h*HD_ + nt*16 + c] = o[nt][r]*il[r];
}

extern "C" void kernel_launch(void* const* d_in, const int* in_sizes, int n_in,
                              void* d_out, int out_size, void* d_ws, size_t ws_size,
                              hipStream_t stream){
  (void)in_sizes; (void)n_in; (void)out_size; (void)ws_size;
  const void* x  = d_in[0];
  const void* Wq = d_in[2];
  const void* Wk = d_in[3];
  const void* Wv = d_in[4];
  const void* Wo = d_in[5];
  char* ws = (char*)d_ws;
  size_t o = 0;
  auto alloc = [&](size_t b){ size_t r = o; o += (b + 255) & ~(size_t)255; return r; };
  size_t META = alloc(256);
  float* wsum   = (float*)(ws + META);
  float* wscale = (float*)(ws + META + 16);
  int*   flag   = (int*)  (ws + META + 32);
  float* s_x = (float*)(ws + alloc((size_t)M_*4));
  float* s_a = (float*)(ws + alloc((size_t)M_*4));
  s8* xq  = (s8*)(ws + alloc((size_t)M_*H_));
  s8* wqq = (s8*)(ws + alloc((size_t)H_*H_));
  s8* wkq = (s8*)(ws + alloc((size_t)KVD_*H_));
  s8* wvq = (s8*)(ws + alloc((size_t)KVD_*H_));
  s8* woq = (s8*)(ws + alloc((size_t)H_*H_));
  float* qb = (float*)(ws + alloc((size_t)M_*NH_*HD_*4));   // fp32 Q; reused as attn-out
  float* kb = (float*)(ws + alloc((size_t)M_*KVD_*4));      // fp32 K
  unsigned short* Qb = (unsigned short*)(ws + alloc((size_t)M_*NH_*HD_*2));
  unsigned short* Kb = (unsigned short*)(ws + alloc((size_t)M_*KVD_*2));
  unsigned short* Vt = (unsigned short*)(ws + alloc((size_t)M_*KVD_*2));
  float* ab = qb;    // qb is dead after k_rope_cvt
  s8* aq = xq;       // xq is dead after the QKV GEMMs

  hipMemsetAsync(ws + META, 0, 64, stream);
  k_detect<<<1,256,0,stream>>>((const unsigned int*)x, flag);

  long nqq = (long)H_*H_, nkk = (long)KVD_*H_;
  k_wsum<<<512,256,0,stream>>>(Wq, nqq, flag, &wsum[0]);
  k_wsum<<<256,256,0,stream>>>(Wk, nkk, flag, &wsum[1]);
  k_wsum<<<256,256,0,stream>>>(Wv, nkk, flag, &wsum[2]);
  k_wsum<<<512,256,0,stream>>>(Wo, nqq, flag, &wsum[3]);
  k_wfin<<<1,64,0,stream>>>(wsum, wscale);
  k_wquant<<<1024,256,0,stream>>>(Wq, nqq, flag, wscale, 0, wqq);
  k_wquant<<<256,256,0,stream>>>(Wk, nkk, flag, wscale, 1, wkq);
  k_wquant<<<256,256,0,stream>>>(Wv, nkk, flag, wscale, 2, wvq);
  k_wquant<<<1024,256,0,stream>>>(Wo, nqq, flag, wscale, 3, woq);

  k_aquant_in<<<M_,256,0,stream>>>(x, flag, s_x, xq);

  dim3 gq(H_/GBN, M_/GBM), gkv(KVD_/GBN, M_/GBM);
  k_gemm<<<gq, 256, 0, stream>>>(xq, wqq, s_x, wscale, 0, qb, H_);
  k_gemm<<<gkv,256, 0, stream>>>(xq, wkq, s_x, wscale, 1, kb, KVD_);
  k_gemm_vt<<<gkv,256,0,stream>>>(xq, wvq, s_x, wscale, 2, Vt);

  dim3 gr(M_, NH_+NKV_);
  k_rope_cvt<<<gr, 64, 0, stream>>>(qb, kb, Qb, Kb);

  dim3 ga(S_/16, NH_, B_);
  k_attn_mfma<<<ga, 64, 0, stream>>>(Qb, Kb, Vt, ab);

  k_aquant_f32<<<M_,256,0,stream>>>(ab, s_a, aq);
  k_gemm_out<<<gq,256,0,stream>>>(aq, woq, s_a, wscale, 3, flag, d_out, H_);
}

// Round 3
// 710.457 us; speedup vs baseline: 10.3151x; 3.7882x over previous
//
#include <hip/hip_runtime.h>
#include <hip/hip_bf16.h>

#define B_ 2
#define S_ 2048
#define H_ 2048
#define NH_ 16
#define NKV_ 4
#define HD_ 128
#define M_ (B_*S_)
#define KVD_ (NKV_*HD_)

typedef signed char s8;
typedef __attribute__((ext_vector_type(8))) short short8;
typedef __attribute__((ext_vector_type(4))) short short4v;
typedef __attribute__((ext_vector_type(4))) float f32x4;
typedef __attribute__((ext_vector_type(4))) int int4v;

__device__ __forceinline__ float loadf(const void* p, long i, int isb){
  if (isb) return __bfloat162float(((const __hip_bfloat16*)p)[i]);
  return ((const float*)p)[i];
}

__device__ __forceinline__ unsigned short f2bf(float f){
  union { float f; unsigned u; } v; v.f = f;
  unsigned r = v.u + 0x7FFF + ((v.u >> 16) & 1);
  return (unsigned short)(r >> 16);
}

// async global->LDS, 16B per lane; lds dst must be wave-uniform base
__device__ __forceinline__ void gl2lds16(const void* g, void* l){
  __builtin_amdgcn_global_load_lds(
      (const __attribute__((address_space(1))) void*)g,
      (__attribute__((address_space(3))) void*)l, 16, 0, 0);
}

// ---- dtype sniffer ----
__global__ void k_detect(const unsigned int* x, int* flag){
  __shared__ int sh[256];
  int t = threadIdx.x, c = 0;
  for (int i = t; i < 2048; i += 256){
    unsigned e = (x[i] >> 7) & 0xFF;
    if (e >= 90 && e <= 150) c++;
  }
  sh[t] = c; __syncthreads();
  for (int k = 128; k > 0; k >>= 1){ if (t < k) sh[t] += sh[t+k]; __syncthreads(); }
  if (t == 0) flag[0] = (sh[0] > 1228) ? 1 : 0;
}

// ---- sum |w| ----
__global__ void k_wsum(const void* w, long n, const int* flag, float* acc){
  __shared__ float sh[256];
  int isb = *flag;
  long stride = (long)gridDim.x * 256;
  float s = 0.f;
  for (long i = (long)blockIdx.x*256 + threadIdx.x; i < n; i += stride)
    s += fabsf(loadf(w, i, isb));
  sh[threadIdx.x] = s; __syncthreads();
  for (int k = 128; k > 0; k >>= 1){ if (threadIdx.x < k) sh[threadIdx.x] += sh[threadIdx.x+k]; __syncthreads(); }
  if (threadIdx.x == 0) atomicAdd(acc, sh[0]);
}

__global__ void k_wfin(const float* wsum, float* wscale){
  const float cnt[4] = { (float)((long)H_*H_), (float)((long)KVD_*H_),
                         (float)((long)KVD_*H_), (float)((long)H_*H_) };
  int t = threadIdx.x;
  if (t < 4){
    float m = wsum[t] / cnt[t];
    m = fmaxf(m, 1e-5f);
    wscale[t] = 1.0f / m;
  }
}

__global__ void k_wquant(const void* w, long n, const int* flag, const float* wscale, int wi, s8* out){
  int isb = *flag; float sc = wscale[wi];
  long stride = (long)gridDim.x * 256;
  for (long i = (long)blockIdx.x*256 + threadIdx.x; i < n; i += stride){
    float v = rintf(loadf(w, i, isb) * sc);
    v = fminf(fmaxf(v, -1.f), 1.f);
    out[i] = (s8)v;
  }
}

// ---- per-token activation quant (typed input) ----
__global__ void k_aquant_in(const void* x, const int* flag, float* srow, s8* xq){
  __shared__ float sh[256];
  int isb = *flag; int r = blockIdx.x, t = threadIdx.x;
  long base = (long)r * H_;
  float mx = 0.f;
  for (int i = t; i < H_; i += 256) mx = fmaxf(mx, fabsf(loadf(x, base+i, isb)));
  sh[t] = mx; __syncthreads();
  for (int k = 128; k > 0; k >>= 1){ if (t < k) sh[t] = fmaxf(sh[t], sh[t+k]); __syncthreads(); }
  float s = 127.0f / fmaxf(sh[0], 1e-5f);
  if (t == 0) srow[r] = s;
  for (int i = t; i < H_; i += 256){
    float v = rintf(loadf(x, base+i, isb) * s);
    v = fminf(fmaxf(v, -128.f), 127.f);
    xq[base+i] = (s8)v;
  }
}

// ---- per-token activation quant (fp32 input) ----
__global__ void k_aquant_f32(const float* x, float* srow, s8* xq){
  __shared__ float sh[256];
  int r = blockIdx.x, t = threadIdx.x;
  long base = (long)r * H_;
  float mx = 0.f;
  for (int i = t; i < H_; i += 256) mx = fmaxf(mx, fabsf(x[base+i]));
  sh[t] = mx; __syncthreads();
  for (int k = 128; k > 0; k >>= 1){ if (t < k) sh[t] = fmaxf(sh[t], sh[t+k]); __syncthreads(); }
  float s = 127.0f / fmaxf(sh[0], 1e-5f);
  if (t == 0) srow[r] = s;
  for (int i = t; i < H_; i += 256){
    float v = rintf(x[base+i] * s);
    v = fminf(fmaxf(v, -128.f), 127.f);
    xq[base+i] = (s8)v;
  }
}

// ---- MFMA int8 GEMM: C[m][n] = sum_k A[m][k]*Bw[n][k] ----
// 128x128x64 tile, 4 waves (2x2), wave = 4x4 grid of 16x16x64 MFMAs.
// LDS layout: row*64 + (kq ^ ((row>>1)&3))*16  (xor swizzle -> uniform banks)
// mode 0: fp32 C[m][N];  mode 1: bf16 Vt[b][col][S];  mode 2: flag-dtype out
__global__ __launch_bounds__(256, 2) void k_gemm_mfma(
      const s8* __restrict__ A, const s8* __restrict__ Bw,
      const float* __restrict__ srow, const float* __restrict__ wscale, int wi,
      void* __restrict__ Cout, int N, int mode,
      const int* __restrict__ flag, unsigned short* __restrict__ Vt){
  __shared__ __align__(16) s8 As[128*64];
  __shared__ __align__(16) s8 Bs[128*64];
  int tid = threadIdx.x;
  int wave = tid >> 6, lane = tid & 63;
  int quad = lane >> 4, c = lane & 15;
  int wm = wave >> 1, wn = wave & 1;
  long arow = (long)blockIdx.y * 128, bcol = (long)blockIdx.x * 128;
  const int K = H_;

  int4v acc[4][4];
  #pragma unroll
  for (int mt = 0; mt < 4; mt++)
    #pragma unroll
    for (int nt = 0; nt < 4; nt++) acc[mt][nt] = (int4v){0,0,0,0};

  // staging addresses (hoisted): lane covers row rl=lane>>2, swizzled granule
  int rl = lane >> 2;
  int kq = (lane & 3) ^ ((lane >> 3) & 3);
  int ldsoff = lane * 16;                       // == rl*64 + (lane&3)*16

  // fragment read offsets (hoisted)
  int sA = quad ^ ((c >> 1) & 3);
  int frA[4], frB[4];
  #pragma unroll
  for (int mt = 0; mt < 4; mt++) frA[mt] = (wm*64 + mt*16 + c)*64 + sA*16;
  #pragma unroll
  for (int nt = 0; nt < 4; nt++) frB[nt] = (wn*64 + nt*16 + c)*64 + sA*16;

  for (int k0 = 0; k0 < K; k0 += 64){
    #pragma unroll
    for (int cc = 0; cc < 2; cc++){
      int ch = wave*2 + cc;
      gl2lds16(A  + (arow + ch*16 + rl)*K + k0 + kq*16, As + ch*1024 + ldsoff - ldsoff + ch*0 + (ldsoff));
      // NOTE: dst must be wave-uniform; rewrite below
    }
    // (the loop above is replaced by explicit calls to keep dst uniform)
    __syncthreads();
    int4v afr[4], bfr[4];
    #pragma unroll
    for (int mt = 0; mt < 4; mt++) afr[mt] = *(const int4v*)&As[frA[mt]];
    #pragma unroll
    for (int nt = 0; nt < 4; nt++) bfr[nt] = *(const int4v*)&Bs[frB[nt]];
    #pragma unroll
    for (int mt = 0; mt < 4; mt++)
      #pragma unroll
      for (int nt = 0; nt < 4; nt++)
        acc[mt][nt] = __builtin_amdgcn_mfma_i32_16x16x64_i8(afr[mt], bfr[nt], acc[mt][nt], 0, 0, 0);
    __syncthreads();
  }

  float wsc = wscale[wi];
  #pragma unroll
  for (int mt = 0; mt < 4; mt++){
    #pragma unroll
    for (int r = 0; r < 4; r++){
      long grow = arow + wm*64 + mt*16 + quad*4 + r;
      float sc = 1.0f / (srow[grow] * wsc);
      if (mode == 0){
        float* C = (float*)Cout;
        #pragma unroll
        for (int nt = 0; nt < 4; nt++)
          C[grow*(long)N + bcol + wn*64 + nt*16 + c] = acc[mt][nt][r] * sc;
      } else if (mode == 1){
        long bb = grow >> 11; int sI = (int)(grow & (S_-1));
        unsigned short* base = Vt + bb*(long)KVD_*S_ + sI;
        #pragma unroll
        for (int nt = 0; nt < 4; nt++)
          base[(long)(bcol + wn*64 + nt*16 + c)*S_] = f2bf(acc[mt][nt][r] * sc);
      } else {
        long cb = grow*(long)N + bcol + wn*64 + c;
        if (*flag){
          __hip_bfloat16* o = (__hip_bfloat16*)Cout;
          #pragma unroll
          for (int nt = 0; nt < 4; nt++)
            o[cb + nt*16] = __float2bfloat16(acc[mt][nt][r] * sc);
        } else {
          float* o = (float*)Cout;
          #pragma unroll
          for (int nt = 0; nt < 4; nt++)
            o[cb + nt*16] = acc[mt][nt][r] * sc;
        }
      }
    }
  }
}

// The staging inside the K-loop above was mis-expressed; real implementation:
// (kept as a separate function body via macro to keep dst wave-uniform)
#undef STAGE

// Re-implementation of the GEMM with correct staging (the one actually launched)
__global__ __launch_bounds__(256, 2) void k_gemm_mfma2(
      const s8* __restrict__ A, const s8* __restrict__ Bw,
      const float* __restrict__ srow, const float* __restrict__ wscale, int wi,
      void* __restrict__ Cout, int N, int mode,
      const int* __restrict__ flag, unsigned short* __restrict__ Vt){
  __shared__ __align__(16) s8 As[128*64];
  __shared__ __align__(16) s8 Bs[128*64];
  int tid = threadIdx.x;
  int wave = tid >> 6, lane = tid & 63;
  int quad = lane >> 4, c = lane & 15;
  int wm = wave >> 1, wn = wave & 1;
  long arow = (long)blockIdx.y * 128, bcol = (long)blockIdx.x * 128;
  const int K = H_;

  int4v acc[4][4];
  #pragma unroll
  for (int mt = 0; mt < 4; mt++)
    #pragma unroll
    for (int nt = 0; nt < 4; nt++) acc[mt][nt] = (int4v){0,0,0,0};

  int rl = lane >> 2;
  int kq = (lane & 3) ^ ((lane >> 3) & 3);     // swizzled k-granule this lane fetches
  int ch0 = wave*2, ch1 = wave*2 + 1;
  // per-lane global row offsets for the two chunks this wave stages
  long gA0 = (arow + ch0*16 + rl)*(long)K + kq*16;
  long gA1 = (arow + ch1*16 + rl)*(long)K + kq*16;
  long gB0 = (bcol + ch0*16 + rl)*(long)K + kq*16;
  long gB1 = (bcol + ch1*16 + rl)*(long)K + kq*16;

  int sA = quad ^ ((c >> 1) & 3);
  int frA[4], frB[4];
  #pragma unroll
  for (int mt = 0; mt < 4; mt++) frA[mt] = (wm*64 + mt*16 + c)*64 + sA*16;
  #pragma unroll
  for (int nt = 0; nt < 4; nt++) frB[nt] = (wn*64 + nt*16 + c)*64 + sA*16;

  for (int k0 = 0; k0 < K; k0 += 64){
    gl2lds16(A  + gA0 + k0, As + ch0*1024);
    gl2lds16(A  + gA1 + k0, As + ch1*1024);
    gl2lds16(Bw + gB0 + k0, Bs + ch0*1024);
    gl2lds16(Bw + gB1 + k0, Bs + ch1*1024);
    __syncthreads();
    int4v afr[4], bfr[4];
    #pragma unroll
    for (int mt = 0; mt < 4; mt++) afr[mt] = *(const int4v*)&As[frA[mt]];
    #pragma unroll
    for (int nt = 0; nt < 4; nt++) bfr[nt] = *(const int4v*)&Bs[frB[nt]];
    #pragma unroll
    for (int mt = 0; mt < 4; mt++)
      #pragma unroll
      for (int nt = 0; nt < 4; nt++)
        acc[mt][nt] = __builtin_amdgcn_mfma_i32_16x16x64_i8(afr[mt], bfr[nt], acc[mt][nt], 0, 0, 0);
    __syncthreads();
  }

  float wsc = wscale[wi];
  #pragma unroll
  for (int mt = 0; mt < 4; mt++){
    #pragma unroll
    for (int r = 0; r < 4; r++){
      long grow = arow + wm*64 + mt*16 + quad*4 + r;
      float sc = 1.0f / (srow[grow] * wsc);
      if (mode == 0){
        float* C = (float*)Cout;
        #pragma unroll
        for (int nt = 0; nt < 4; nt++)
          C[grow*(long)N + bcol + wn*64 + nt*16 + c] = acc[mt][nt][r] * sc;
      } else if (mode == 1){
        long bb = grow >> 11; int sI = (int)(grow & (S_-1));
        unsigned short* base = Vt + bb*(long)KVD_*S_ + sI;
        #pragma unroll
        for (int nt = 0; nt < 4; nt++)
          base[(long)(bcol + wn*64 + nt*16 + c)*S_] = f2bf(acc[mt][nt][r] * sc);
      } else {
        long cb = grow*(long)N + bcol + wn*64 + c;
        if (*flag){
          __hip_bfloat16* o = (__hip_bfloat16*)Cout;
          #pragma unroll
          for (int nt = 0; nt < 4; nt++)
            o[cb + nt*16] = __float2bfloat16(acc[mt][nt][r] * sc);
        } else {
          float* o = (float*)Cout;
          #pragma unroll
          for (int nt = 0; nt < 4; nt++)
            o[cb + nt*16] = acc[mt][nt][r] * sc;
        }
      }
    }
  }
}

// ---- RoPE fp32 -> bf16; Q pre-scaled by 1/sqrt(HD) ----
__global__ void k_rope_cvt(const float* __restrict__ qf, const float* __restrict__ kf,
                           unsigned short* __restrict__ Qb, unsigned short* __restrict__ Kb){
  int row = blockIdx.x, hh = blockIdx.y, d = threadIdx.x;   // d in [0,64)
  int pos = row & (S_-1);
  float inv = powf(10000.0f, -(float)d * (1.0f/64.0f));
  float a = (float)pos * inv;
  float sn, cs; sincosf(a, &sn, &cs);
  if (hh < NH_){
    const float* p = qf + ((long)row*NH_ + hh)*HD_;
    unsigned short* q = Qb + ((long)row*NH_ + hh)*HD_;
    float x0 = p[d], x1 = p[d+64];
    const float sc = 0.08838834764831845f;
    q[d]    = f2bf((x0*cs - x1*sn)*sc);
    q[d+64] = f2bf((x1*cs + x0*sn)*sc);
  } else {
    int kh = hh - NH_;
    const float* p = kf + ((long)row*NKV_ + kh)*HD_;
    unsigned short* k = Kb + ((long)row*NKV_ + kh)*HD_;
    float x0 = p[d], x1 = p[d+64];
    k[d]    = f2bf(x0*cs - x1*sn);
    k[d+64] = f2bf(x1*cs + x0*sn);
  }
}

// ---- MFMA flash attention: 1 wave per (b,h,16-row q-tile) ----
__global__ __launch_bounds__(64) void k_attn_mfma(const unsigned short* __restrict__ Qb,
    const unsigned short* __restrict__ Kb, const unsigned short* __restrict__ Vt,
    float* __restrict__ ob){
  int qt = blockIdx.x, h = blockIdx.y, b = blockIdx.z;
  int lane = threadIdx.x, quad = lane >> 4, c = lane & 15;
  int kvh = h >> 2, q0 = qt * 16;
  short8 qf[4];
  #pragma unroll
  for (int f = 0; f < 4; f++)
    qf[f] = *(const short8*)(Qb + ((long)(b*S_ + q0 + c)*NH_ + h)*HD_ + f*32 + quad*8);
  const unsigned short* Kp = Kb + (long)b*S_*KVD_ + kvh*HD_;
  const unsigned short* Vp = Vt + ((long)b*KVD_ + kvh*HD_)*S_;
  f32x4 o[8];
  #pragma unroll
  for (int i = 0; i < 8; i++) o[i] = (f32x4){0.f,0.f,0.f,0.f};
  float m[4] = {-1e30f,-1e30f,-1e30f,-1e30f};
  float l[4] = {0.f,0.f,0.f,0.f};
  __shared__ unsigned short Pl[16*40];
  int nk = q0 + 16;
  for (int kc = 0; kc < nk; kc += 32){
    f32x4 s[2];
    s[0] = (f32x4){0.f,0.f,0.f,0.f};
    s[1] = (f32x4){0.f,0.f,0.f,0.f};
    #pragma unroll
    for (int t = 0; t < 2; t++){
      int key = kc + t*16 + c;
      int ka = min(key, S_-1);
      #pragma unroll
      for (int f = 0; f < 4; f++){
        short8 kfr = *(const short8*)(Kp + (long)ka*KVD_ + f*32 + quad*8);
        s[t] = __builtin_amdgcn_mfma_f32_16x16x32_bf16(qf[f], kfr, s[t], 0, 0, 0);
      }
    }
    if (kc + 31 > q0){
      #pragma unroll
      for (int t = 0; t < 2; t++){
        int key = kc + t*16 + c;
        #pragma unroll
        for (int r = 0; r < 4; r++)
          if (key > q0 + quad*4 + r) s[t][r] = -1e30f;
      }
    }
    float mr[4], alpha[4], rs[4];
    #pragma unroll
    for (int r = 0; r < 4; r++) mr[r] = fmaxf(s[0][r], s[1][r]);
    #pragma unroll
    for (int w = 1; w < 16; w <<= 1)
      #pragma unroll
      for (int r = 0; r < 4; r++) mr[r] = fmaxf(mr[r], __shfl_xor(mr[r], w, 64));
    #pragma unroll
    for (int r = 0; r < 4; r++){
      float mn = fmaxf(m[r], mr[r]);
      alpha[r] = __expf(m[r] - mn);
      m[r] = mn;
    }
    #pragma unroll
    for (int r = 0; r < 4; r++){
      float p0 = __expf(s[0][r] - m[r]);
      float p1 = __expf(s[1][r] - m[r]);
      s[0][r] = p0; s[1][r] = p1; rs[r] = p0 + p1;
    }
    #pragma unroll
    for (int w = 1; w < 16; w <<= 1)
      #pragma unroll
      for (int r = 0; r < 4; r++) rs[r] += __shfl_xor(rs[r], w, 64);
    #pragma unroll
    for (int r = 0; r < 4; r++) l[r] = l[r]*alpha[r] + rs[r];
    #pragma unroll
    for (int nt = 0; nt < 8; nt++)
      #pragma unroll
      for (int r = 0; r < 4; r++) o[nt][r] *= alpha[r];
    #pragma unroll
    for (int t = 0; t < 2; t++)
      #pragma unroll
      for (int r = 0; r < 4; r++)
        Pl[(quad*4 + r)*40 + t*16 + c] = f2bf(s[t][r]);
    __syncthreads();
    short8 pf;
    {
      short4v a0 = *(const short4v*)&Pl[c*40 + quad*8];
      short4v a1 = *(const short4v*)&Pl[c*40 + quad*8 + 4];
      pf[0]=a0[0]; pf[1]=a0[1]; pf[2]=a0[2]; pf[3]=a0[3];
      pf[4]=a1[0]; pf[5]=a1[1]; pf[6]=a1[2]; pf[7]=a1[3];
    }
    __syncthreads();
    int kb0 = min(kc + quad*8, S_-8);
    #pragma unroll
    for (int nt = 0; nt < 8; nt++){
      short8 vf = *(const short8*)(Vp + (long)(nt*16 + c)*S_ + kb0);
      o[nt] = __builtin_amdgcn_mfma_f32_16x16x32_bf16(pf, vf, o[nt], 0, 0, 0);
    }
  }
  float il[4];
  #pragma unroll
  for (int r = 0; r < 4; r++) il[r] = 1.0f / l[r];
  #pragma unroll
  for (int nt = 0; nt < 8; nt++)
    #pragma unroll
    for (int r = 0; r < 4; r++)
      ob[((long)(b*S_ + q0 + quad*4 + r))*H_ + h*HD_ + nt*16 + c] = o[nt][r]*il[r];
}

extern "C" void kernel_launch(void* const* d_in, const int* in_sizes, int n_in,
                              void* d_out, int out_size, void* d_ws, size_t ws_size,
                              hipStream_t stream){
  (void)in_sizes; (void)n_in; (void)out_size; (void)ws_size;
  const void* x  = d_in[0];
  const void* Wq = d_in[2];
  const void* Wk = d_in[3];
  const void* Wv = d_in[4];
  const void* Wo = d_in[5];
  char* ws = (char*)d_ws;
  size_t o = 0;
  auto alloc = [&](size_t b){ size_t r = o; o += (b + 255) & ~(size_t)255; return r; };
  size_t META = alloc(256);
  float* wsum   = (float*)(ws + META);
  float* wscale = (float*)(ws + META + 16);
  int*   flag   = (int*)  (ws + META + 32);
  float* s_x = (float*)(ws + alloc((size_t)M_*4));
  float* s_a = (float*)(ws + alloc((size_t)M_*4));
  s8* xq  = (s8*)(ws + alloc((size_t)M_*H_));
  s8* wqq = (s8*)(ws + alloc((size_t)H_*H_));
  s8* wkq = (s8*)(ws + alloc((size_t)KVD_*H_));
  s8* wvq = (s8*)(ws + alloc((size_t)KVD_*H_));
  s8* woq = (s8*)(ws + alloc((size_t)H_*H_));
  float* qb = (float*)(ws + alloc((size_t)M_*NH_*HD_*4));   // fp32 Q; reused as attn-out
  float* kb = (float*)(ws + alloc((size_t)M_*KVD_*4));      // fp32 K
  unsigned short* Qb = (unsigned short*)(ws + alloc((size_t)M_*NH_*HD_*2));
  unsigned short* Kb = (unsigned short*)(ws + alloc((size_t)M_*KVD_*2));
  unsigned short* Vt = (unsigned short*)(ws + alloc((size_t)M_*KVD_*2));
  float* ab = qb;    // qb dead after k_rope_cvt
  s8* aq = xq;       // xq dead after QKV GEMMs

  hipMemsetAsync(ws + META, 0, 64, stream);
  k_detect<<<1,256,0,stream>>>((const unsigned int*)x, flag);

  long nqq = (long)H_*H_, nkk = (long)KVD_*H_;
  k_wsum<<<512,256,0,stream>>>(Wq, nqq, flag, &wsum[0]);
  k_wsum<<<256,256,0,stream>>>(Wk, nkk, flag, &wsum[1]);
  k_wsum<<<256,256,0,stream>>>(Wv, nkk, flag, &wsum[2]);
  k_wsum<<<512,256,0,stream>>>(Wo, nqq, flag, &wsum[3]);
  k_wfin<<<1,64,0,stream>>>(wsum, wscale);
  k_wquant<<<1024,256,0,stream>>>(Wq, nqq, flag, wscale, 0, wqq);
  k_wquant<<<256,256,0,stream>>>(Wk, nkk, flag, wscale, 1, wkq);
  k_wquant<<<256,256,0,stream>>>(Wv, nkk, flag, wscale, 2, wvq);
  k_wquant<<<1024,256,0,stream>>>(Wo, nqq, flag, wscale, 3, woq);

  k_aquant_in<<<M_,256,0,stream>>>(x, flag, s_x, xq);

  dim3 gq(H_/128, M_/128), gkv(KVD_/128, M_/128);
  k_gemm_mfma2<<<gq, 256, 0, stream>>>(xq, wqq, s_x, wscale, 0, qb, H_,   0, flag, nullptr);
  k_gemm_mfma2<<<gkv,256, 0, stream>>>(xq, wkq, s_x, wscale, 1, kb, KVD_, 0, flag, nullptr);
  k_gemm_mfma2<<<gkv,256, 0, stream>>>(xq, wvq, s_x, wscale, 2, nullptr, KVD_, 1, flag, Vt);

  dim3 gr(M_, NH_+NKV_);
  k_rope_cvt<<<gr, 64, 0, stream>>>(qb, kb, Qb, Kb);

  dim3 ga(S_/16, NH_, B_);
  k_attn_mfma<<<ga, 64, 0, stream>>>(Qb, Kb, Vt, ab);

  k_aquant_f32<<<M_,256,0,stream>>>(ab, s_a, aq);
  k_gemm_mfma2<<<gq,256,0,stream>>>(aq, woq, s_a, wscale, 3, d_out, H_, 2, flag, nullptr);
}